// Round 2
// baseline (289.977 us; speedup 1.0000x reference)
//
#include <hip/hip_runtime.h>
#include <cstdint>

// Problem constants (fixed by the reference): B=16, S=1, Dm=4096, H=32, Hd=128, P=2048
#define DM 4096
#define NB 16
#define NH 32
#define HD 128
#define PP 2048

typedef __attribute__((ext_vector_type(8))) short bf16x8;
typedef __attribute__((ext_vector_type(4))) float f32x4;

__device__ inline short f2bf(float f) {
  // round-to-nearest-even fp32 -> bf16
  uint32_t u = __float_as_uint(f);
  u += 0x7fffu + ((u >> 16) & 1u);
  return (short)(u >> 16);
}

__device__ inline float bf2f(short s) {
  return __uint_as_float(((uint32_t)(uint16_t)s) << 16);
}

// Computes O[b][jt+n] = sum_d A[b][d] * W[jt+n][d] for a 16-wide column tile.
// A: (16, 4096) fp32, W: (4096, 4096) fp32 row-major. 256 threads = 4 waves, K split
// across waves, MFMA fragments gathered directly from global (no LDS staging),
// final cross-wave reduction through LDS.
// Precision: hi/lo bf16 split (3 MFMAs) -> ~2^-17 relative error, still memory-bound.
__device__ inline void gemv16_block(const float* __restrict__ A,
                                    const float* __restrict__ W,
                                    float* __restrict__ O, int jt) {
  const int wave = threadIdx.x >> 6;
  const int lane = threadIdx.x & 63;
  const int m = lane & 15;   // A-row (batch) / B-row (output column) within tile
  const int kg = lane >> 4;  // k-group 0..3, 8 elems each
  const float* arow = A + (size_t)m * DM;
  const float* wrow = W + (size_t)(jt + m) * DM;
  const int kbase = wave * (DM / 4) + kg * 8;
  f32x4 acc = {0.f, 0.f, 0.f, 0.f};
#pragma unroll 2
  for (int kb = 0; kb < (DM / 4) / 32; ++kb) {
    const int k = kbase + kb * 32;
    float4 xa = *(const float4*)(arow + k);
    float4 xb = *(const float4*)(arow + k + 4);
    float4 wa = *(const float4*)(wrow + k);
    float4 wb = *(const float4*)(wrow + k + 4);
    float xs[8] = {xa.x, xa.y, xa.z, xa.w, xb.x, xb.y, xb.z, xb.w};
    float ws[8] = {wa.x, wa.y, wa.z, wa.w, wb.x, wb.y, wb.z, wb.w};
    bf16x8 ah, al, wh, wl;
#pragma unroll
    for (int i = 0; i < 8; ++i) {
      short h = f2bf(xs[i]);
      ah[i] = h;
      al[i] = f2bf(xs[i] - bf2f(h));
      short g = f2bf(ws[i]);
      wh[i] = g;
      wl[i] = f2bf(ws[i] - bf2f(g));
    }
    acc = __builtin_amdgcn_mfma_f32_16x16x32_bf16(ah, wh, acc, 0, 0, 0);
    acc = __builtin_amdgcn_mfma_f32_16x16x32_bf16(ah, wl, acc, 0, 0, 0);
    acc = __builtin_amdgcn_mfma_f32_16x16x32_bf16(al, wh, acc, 0, 0, 0);
  }
  // D layout: n = lane&15, mrow = (lane>>4)*4 + reg
  __shared__ float red[4][256];
  red[wave][lane * 4 + 0] = acc[0];
  red[wave][lane * 4 + 1] = acc[1];
  red[wave][lane * 4 + 2] = acc[2];
  red[wave][lane * 4 + 3] = acc[3];
  __syncthreads();
  const int t = threadIdx.x;
  float s = red[0][t] + red[1][t] + red[2][t] + red[3][t];
  const int l = t >> 2, r = t & 3;
  const int bb = ((l >> 4) << 2) + r;  // batch row of D
  const int n = l & 15;                // column within tile
  O[(size_t)bb * DM + jt + n] = s;
}

__global__ __launch_bounds__(256) void qkv_proj_kernel(
    const float* __restrict__ x,
    const float* __restrict__ wq, const float* __restrict__ wk,
    const float* __restrict__ wv,
    float* __restrict__ oq, float* __restrict__ ok, float* __restrict__ ov) {
  const int g = blockIdx.x >> 8;           // 0=q 1=k 2=v
  const int jt = (blockIdx.x & 255) << 4;  // 16-wide column tile
  const float* w = (g == 0) ? wq : (g == 1) ? wk : wv;
  float* o = (g == 0) ? oq : (g == 1) ? ok : ov;
  gemv16_block(x, w, o, jt);
}

__global__ __launch_bounds__(256) void oproj_kernel(
    const float* __restrict__ a, const float* __restrict__ w,
    float* __restrict__ o) {
  gemv16_block(a, w, o, blockIdx.x << 4);
}

// One block per (b, h): RoPE q and k_new, scores over 2049 positions, softmax, PV.
__global__ __launch_bounds__(512) void attn_kernel(
    const float* __restrict__ q_raw, const float* __restrict__ k_raw,
    const float* __restrict__ v_raw,
    const float* __restrict__ cache_k, const float* __restrict__ cache_v,
    const float* __restrict__ fr, const float* __restrict__ fi,
    float* __restrict__ attn_out) {
  const int b = blockIdx.x >> 5;
  const int h = blockIdx.x & 31;
  const int t = threadIdx.x;

  __shared__ float q[HD], kn[HD], vn[HD];
  __shared__ float sc[PP + 4];
  __shared__ float pvred[16][HD];
  __shared__ float wredm[8], wreds[8];

  const float* qh = q_raw + (size_t)b * DM + h * HD;
  const float* kh = k_raw + (size_t)b * DM + h * HD;
  const float* vh = v_raw + (size_t)b * DM + h * HD;

  if (t < 64) {
    // RoPE: out[j] = x[2j]*fr[j] - x[2j+1]*fi[j]; out[j+64] = x[2j]*fi[j] + x[2j+1]*fr[j]
    float f_r = fr[t], f_i = fi[t];
    float qr = qh[2 * t], qi = qh[2 * t + 1];
    float kr = kh[2 * t], ki = kh[2 * t + 1];
    q[t] = qr * f_r - qi * f_i;
    q[t + 64] = qr * f_i + qi * f_r;
    kn[t] = kr * f_r - ki * f_i;
    kn[t + 64] = kr * f_i + ki * f_r;
  } else if (t >= 128 && t < 256) {
    vn[t - 128] = vh[t - 128];
  }
  __syncthreads();

  const float scale = 0.08838834764831845f;  // 1/sqrt(128)
  const float* Kb = cache_k + (size_t)b * (PP * (size_t)DM) + (size_t)h * HD;

  // score for the appended position (p = 2048) by the last wave
  if (t >= 448) {
    const int lane = t - 448;
    float p = q[lane] * kn[lane] + q[lane + 64] * kn[lane + 64];
#pragma unroll
    for (int off = 32; off; off >>= 1) p += __shfl_down(p, off);
    if (lane == 0) sc[PP] = p * scale;
  }

  // cached positions: thread t handles rows p = t, t+512, t+1024, t+1536
  for (int p = t; p < PP; p += 512) {
    const float* kp = Kb + (size_t)p * DM;
    float acc0 = 0.f, acc1 = 0.f;
#pragma unroll
    for (int d4 = 0; d4 < 64; d4 += 4) {
      float4 k0 = *(const float4*)(kp + d4);
      float4 k1 = *(const float4*)(kp + d4 + 64);
      acc0 += q[d4] * k0.x + q[d4 + 1] * k0.y + q[d4 + 2] * k0.z + q[d4 + 3] * k0.w;
      acc1 += q[d4 + 64] * k1.x + q[d4 + 65] * k1.y + q[d4 + 66] * k1.z + q[d4 + 67] * k1.w;
    }
    sc[p] = (acc0 + acc1) * scale;
  }
  __syncthreads();

  // block max
  float mloc = -1e30f;
  for (int p = t; p < PP + 1; p += 512) mloc = fmaxf(mloc, sc[p]);
#pragma unroll
  for (int off = 32; off; off >>= 1) mloc = fmaxf(mloc, __shfl_xor(mloc, off));
  if ((t & 63) == 0) wredm[t >> 6] = mloc;
  __syncthreads();
  const float mglob =
      fmaxf(fmaxf(fmaxf(wredm[0], wredm[1]), fmaxf(wredm[2], wredm[3])),
            fmaxf(fmaxf(wredm[4], wredm[5]), fmaxf(wredm[6], wredm[7])));

  // exp + block sum
  float sloc = 0.f;
  for (int p = t; p < PP + 1; p += 512) {
    float e = __expf(sc[p] - mglob);
    sc[p] = e;
    sloc += e;
  }
#pragma unroll
  for (int off = 32; off; off >>= 1) sloc += __shfl_xor(sloc, off);
  if ((t & 63) == 0) wreds[t >> 6] = sloc;
  __syncthreads();
  const float ssum = wreds[0] + wreds[1] + wreds[2] + wreds[3] +
                     wreds[4] + wreds[5] + wreds[6] + wreds[7];
  const float inv = 1.0f / ssum;

  // PV: group g handles positions p = g, g+16, ...; 32 lanes cover d via float4
  const int g = t >> 5;
  const int dq = (t & 31) << 2;
  const float* Vb = cache_v + (size_t)b * (PP * (size_t)DM) + (size_t)h * HD;
  float4 a0 = {0.f, 0.f, 0.f, 0.f}, a1 = {0.f, 0.f, 0.f, 0.f};
  for (int p = g; p < PP; p += 32) {
    float pr0 = sc[p];
    float4 v0 = *(const float4*)(Vb + (size_t)p * DM + dq);
    a0.x += pr0 * v0.x; a0.y += pr0 * v0.y; a0.z += pr0 * v0.z; a0.w += pr0 * v0.w;
    float pr1 = sc[p + 16];
    float4 v1 = *(const float4*)(Vb + (size_t)(p + 16) * DM + dq);
    a1.x += pr1 * v1.x; a1.y += pr1 * v1.y; a1.z += pr1 * v1.z; a1.w += pr1 * v1.w;
  }
  a0.x += a1.x; a0.y += a1.y; a0.z += a1.z; a0.w += a1.w;
  if (g == 0) {
    float pr = sc[PP];
    a0.x += pr * vn[dq]; a0.y += pr * vn[dq + 1];
    a0.z += pr * vn[dq + 2]; a0.w += pr * vn[dq + 3];
  }
  pvred[g][dq + 0] = a0.x;
  pvred[g][dq + 1] = a0.y;
  pvred[g][dq + 2] = a0.z;
  pvred[g][dq + 3] = a0.w;
  __syncthreads();
  if (t < HD) {
    float o = 0.f;
#pragma unroll
    for (int gg = 0; gg < 16; ++gg) o += pvred[gg][t];
    attn_out[(size_t)b * DM + h * HD + t] = o * inv;
  }
}

extern "C" void kernel_launch(void* const* d_in, const int* in_sizes, int n_in,
                              void* d_out, int out_size, void* d_ws, size_t ws_size,
                              hipStream_t stream) {
  const float* x = (const float*)d_in[0];
  const float* cache_k = (const float*)d_in[1];
  const float* cache_v = (const float*)d_in[2];
  const float* fr = (const float*)d_in[3];
  const float* fi = (const float*)d_in[4];
  const float* dwq = (const float*)d_in[5];
  const float* dwk = (const float*)d_in[6];
  const float* dwv = (const float*)d_in[7];
  const float* dwo = (const float*)d_in[8];
  float* out = (float*)d_out;

  float* qraw = (float*)d_ws;           // 16*4096
  float* kraw = qraw + NB * DM;         // 16*4096
  float* vraw = kraw + NB * DM;         // 16*4096
  float* aout = vraw + NB * DM;         // 16*4096

  qkv_proj_kernel<<<768, 256, 0, stream>>>(x, dwq, dwk, dwv, qraw, kraw, vraw);
  attn_kernel<<<512, 512, 0, stream>>>(qraw, kraw, vraw, cache_k, cache_v, fr, fi, aout);
  oproj_kernel<<<256, 256, 0, stream>>>(aout, dwo, out);
}

// Round 4
// 246.309 us; speedup vs baseline: 1.1773x; 1.1773x over previous
//
#include <hip/hip_runtime.h>
#include <cstdint>

// Problem constants: B=16, S=1, Dm=4096, H=32, Hd=128, P=2048
#define DM 4096
#define NB 16
#define NH 32
#define HD 128
#define PP 2048
#define NCHUNK 32
#define CROWS 64     // PP / NCHUNK
#define PSTRIDE 132  // per-head partial: 128 o + m + s + 2 pad (16B-aligned stride)

typedef __attribute__((ext_vector_type(8))) short bf16x8;
typedef __attribute__((ext_vector_type(4))) float f32x4;

__device__ inline short f2bf(float f) {
  uint32_t u = __float_as_uint(f);
  u += 0x7fffu + ((u >> 16) & 1u);
  return (short)(u >> 16);
}
__device__ inline float bf2f(short s) {
  return __uint_as_float(((uint32_t)(uint16_t)s) << 16);
}
__device__ inline f32x4 ntld4(const float* p) {
  return __builtin_nontemporal_load(reinterpret_cast<const f32x4*>(p));
}

// O[b][col(jt+n)] = sum_d A[b][d] * W[jt+n][d], 16-wide column tile.
// NW waves split K. ROPE: apply rotary remap to the output (q/k projections):
//   pair (2j,2j+1) within head -> out[j] = e*fr - o*fi, out[64+j] = e*fi + o*fr.
template <int NW, bool ROPE>
__device__ inline void gemv16(const float* __restrict__ A,
                              const float* __restrict__ W,
                              float* __restrict__ O, int jt,
                              const float* __restrict__ fr,
                              const float* __restrict__ fi) {
  const int wave = threadIdx.x >> 6;
  const int lane = threadIdx.x & 63;
  const int m = lane & 15;   // A-row (batch) / W-row (output col) in tile
  const int kg = lane >> 4;  // k-group 0..3
  const float* arow = A + (size_t)m * DM;
  const float* wrow = W + (size_t)(jt + m) * DM;
  const int kbase = wave * (DM / NW) + kg * 8;
  f32x4 acc = {0.f, 0.f, 0.f, 0.f};
#pragma unroll 2
  for (int kb = 0; kb < (DM / NW) / 32; ++kb) {
    const int k = kbase + kb * 32;
    float4 xa = *(const float4*)(arow + k);
    float4 xb = *(const float4*)(arow + k + 4);
    f32x4 wa = ntld4(wrow + k);
    f32x4 wb = ntld4(wrow + k + 4);
    float xs[8] = {xa.x, xa.y, xa.z, xa.w, xb.x, xb.y, xb.z, xb.w};
    float ws[8] = {wa.x, wa.y, wa.z, wa.w, wb.x, wb.y, wb.z, wb.w};
    bf16x8 ah, al, wh, wl;
#pragma unroll
    for (int i = 0; i < 8; ++i) {
      short hsh = f2bf(xs[i]);
      ah[i] = hsh;
      al[i] = f2bf(xs[i] - bf2f(hsh));
      short gsh = f2bf(ws[i]);
      wh[i] = gsh;
      wl[i] = f2bf(ws[i] - bf2f(gsh));
    }
    acc = __builtin_amdgcn_mfma_f32_16x16x32_bf16(ah, wh, acc, 0, 0, 0);
    acc = __builtin_amdgcn_mfma_f32_16x16x32_bf16(ah, wl, acc, 0, 0, 0);
    acc = __builtin_amdgcn_mfma_f32_16x16x32_bf16(al, wh, acc, 0, 0, 0);
  }
  __shared__ float red[NW][256];
  red[wave][lane * 4 + 0] = acc[0];
  red[wave][lane * 4 + 1] = acc[1];
  red[wave][lane * 4 + 2] = acc[2];
  red[wave][lane * 4 + 3] = acc[3];
  __syncthreads();
  const int t = threadIdx.x;
  float s = 0.f;
  if (t < 256) {
#pragma unroll
    for (int w = 0; w < NW; ++w) s += red[w][t];
  }
  float part = 0.f;
  if (ROPE) {
    // exchange pair-partner sums: partner thread is t^4 (adjacent output col)
    __syncthreads();
    if (t < 256) red[0][t] = s;
    __syncthreads();
    if (t < 256) part = red[0][t ^ 4];
  }
  if (t < 256) {
    const int l = t >> 2, r = t & 3;
    const int bb = ((l >> 4) << 2) + r;  // batch row of D
    const int n = l & 15;                // column within tile
    const int c = jt + n;
    float val;
    int oc;
    if (ROPE) {
      const int j = (c & 127) >> 1;
      const float f_r = fr[j], f_i = fi[j];
      if ((c & 1) == 0) {  // even: x_even = s, partner = x_odd
        val = s * f_r - part * f_i;
        oc = (c & ~127) + j;
      } else {             // odd: x_even = part, x_odd = s
        val = part * f_i + s * f_r;
        oc = (c & ~127) + 64 + j;
      }
    } else {
      val = s;
      oc = c;
    }
    O[(size_t)bb * DM + oc] = val;
  }
}

__global__ __launch_bounds__(256) void qkv_proj_kernel(
    const float* __restrict__ x, const float* __restrict__ wq,
    const float* __restrict__ wk, const float* __restrict__ wv,
    const float* __restrict__ fr, const float* __restrict__ fi,
    float* __restrict__ oq, float* __restrict__ ok, float* __restrict__ ov) {
  const int g = blockIdx.x >> 8;
  const int jt = (blockIdx.x & 255) << 4;
  if (g == 0)
    gemv16<4, true>(x, wq, oq, jt, fr, fi);
  else if (g == 1)
    gemv16<4, true>(x, wk, ok, jt, fr, fi);
  else
    gemv16<4, false>(x, wv, ov, jt, nullptr, nullptr);
}

__global__ __launch_bounds__(1024, 4) void oproj_kernel(
    const float* __restrict__ a, const float* __restrict__ w,
    float* __restrict__ o) {
  gemv16<16, false>(a, w, o, blockIdx.x << 4, nullptr, nullptr);
}

// One block per (b, chunk): streams K[b][c*64..+64][*][*] (1MB contiguous) then
// V likewise. Computes chunk-local scores for ALL 32 heads, partial softmax
// (m, s) and unnormalized PV partials -> part[b][c][h][132].
__global__ __launch_bounds__(512) void attn_chunk_kernel(
    const float* __restrict__ qrope, const float* __restrict__ cache_k,
    const float* __restrict__ cache_v, float* __restrict__ part) {
  const int b = blockIdx.x >> 5;
  const int c = blockIdx.x & 31;
  const int t = threadIdx.x;
  __shared__ float sc[NH][CROWS];

  // thread t owns 8 q-floats, constant across rows:
  //   float4 #1 at 4t (head h1 = t>>5), float4 #2 at 2048+4t (head h1+16)
  const float4 qa = *(const float4*)(qrope + (size_t)b * DM + 4 * t);
  const float4 qb = *(const float4*)(qrope + (size_t)b * DM + 2048 + 4 * t);
  const int h1 = t >> 5;
  const int h2 = h1 + 16;
  const float scale = 0.08838834764831845f;  // 1/sqrt(128)

  const float* Kb = cache_k + ((size_t)b * PP + (size_t)c * CROWS) * DM;
#pragma unroll 2
  for (int r = 0; r < CROWS; ++r) {
    const float* krow = Kb + (size_t)r * DM + 4 * t;
    f32x4 k1 = ntld4(krow);
    f32x4 k2 = ntld4(krow + 2048);
    float p1 = qa.x * k1.x + qa.y * k1.y + qa.z * k1.z + qa.w * k1.w;
    float p2 = qb.x * k2.x + qb.y * k2.y + qb.z * k2.z + qb.w * k2.w;
#pragma unroll
    for (int off = 1; off <= 16; off <<= 1) {
      p1 += __shfl_xor(p1, off);
      p2 += __shfl_xor(p2, off);
    }
    if ((t & 31) == 0) {
      sc[h1][r] = p1 * scale;
      sc[h2][r] = p2 * scale;
    }
  }
  __syncthreads();

  // per-head chunk-local softmax: 16 threads per head, 4 scores each
  const int hh = t >> 4, u = t & 15;
  float4 sv4 = *(const float4*)(&sc[hh][u * 4]);
  float mx = fmaxf(fmaxf(sv4.x, sv4.y), fmaxf(sv4.z, sv4.w));
#pragma unroll
  for (int off = 1; off <= 8; off <<= 1) mx = fmaxf(mx, __shfl_xor(mx, off));
  float e0 = __expf(sv4.x - mx), e1 = __expf(sv4.y - mx);
  float e2 = __expf(sv4.z - mx), e3 = __expf(sv4.w - mx);
  float4 ev = {e0, e1, e2, e3};
  *(float4*)(&sc[hh][u * 4]) = ev;  // in-place: e values replace scores
  float sm = (e0 + e1) + (e2 + e3);
#pragma unroll
  for (int off = 1; off <= 8; off <<= 1) sm += __shfl_xor(sm, off);
  float* pb = part + ((size_t)(b * NCHUNK + c) * NH) * PSTRIDE;
  if (u == 0) {
    pb[hh * PSTRIDE + 128] = mx;
    pb[hh * PSTRIDE + 129] = sm;
  }
  __syncthreads();

  // PV: same thread->dim mapping as score phase
  const float* Vb = cache_v + ((size_t)b * PP + (size_t)c * CROWS) * DM;
  f32x4 a1 = {0.f, 0.f, 0.f, 0.f}, a2 = {0.f, 0.f, 0.f, 0.f};
#pragma unroll 2
  for (int r = 0; r < CROWS; ++r) {
    const float* vrow = Vb + (size_t)r * DM + 4 * t;
    f32x4 v1 = ntld4(vrow);
    f32x4 v2 = ntld4(vrow + 2048);
    float w1 = sc[h1][r], w2 = sc[h2][r];
    a1[0] += w1 * v1.x; a1[1] += w1 * v1.y; a1[2] += w1 * v1.z; a1[3] += w1 * v1.w;
    a2[0] += w2 * v2.x; a2[1] += w2 * v2.y; a2[2] += w2 * v2.z; a2[3] += w2 * v2.w;
  }
  const int dbase = (4 * t) & 127;
  float4 o1 = {a1[0], a1[1], a1[2], a1[3]};
  float4 o2 = {a2[0], a2[1], a2[2], a2[3]};
  *(float4*)(pb + h1 * PSTRIDE + dbase) = o1;
  *(float4*)(pb + h2 * PSTRIDE + dbase) = o2;
}

// One block per (b, h): merge 32 chunk partials + the appended position.
__global__ __launch_bounds__(128) void attn_combine_kernel(
    const float* __restrict__ qrope, const float* __restrict__ krope,
    const float* __restrict__ vraw, const float* __restrict__ part,
    float* __restrict__ aout) {
  const int b = blockIdx.x >> 5;
  const int h = blockIdx.x & 31;
  const int d = threadIdx.x;
  __shared__ float red2[2];
  __shared__ float mv[NCHUNK], sv[NCHUNK], ec[NCHUNK];
  const size_t qoff = (size_t)b * DM + h * HD + d;
  float p = qrope[qoff] * krope[qoff];
#pragma unroll
  for (int off = 1; off <= 32; off <<= 1) p += __shfl_xor(p, off);
  if ((d & 63) == 0) red2[d >> 6] = p;
  const float* pb = part + ((size_t)b * NCHUNK * NH + h) * PSTRIDE;
  if (d < NCHUNK) {
    mv[d] = pb[(size_t)d * NH * PSTRIDE + 128];
    sv[d] = pb[(size_t)d * NH * PSTRIDE + 129];
  }
  __syncthreads();
  const float scale = 0.08838834764831845f;
  const float snew = (red2[0] + red2[1]) * scale;
  float M = snew;
#pragma unroll
  for (int c = 0; c < NCHUNK; ++c) M = fmaxf(M, mv[c]);
  if (d < NCHUNK) ec[d] = __expf(mv[d] - M);
  __syncthreads();
  const float en = __expf(snew - M);
  float S = en;
  float acc = en * vraw[qoff];
#pragma unroll 4
  for (int c = 0; c < NCHUNK; ++c) {
    acc += ec[c] * pb[(size_t)c * NH * PSTRIDE + d];
    S += ec[c] * sv[c];
  }
  aout[qoff] = acc / S;
}

extern "C" void kernel_launch(void* const* d_in, const int* in_sizes, int n_in,
                              void* d_out, int out_size, void* d_ws, size_t ws_size,
                              hipStream_t stream) {
  const float* x = (const float*)d_in[0];
  const float* cache_k = (const float*)d_in[1];
  const float* cache_v = (const float*)d_in[2];
  const float* fr = (const float*)d_in[3];
  const float* fi = (const float*)d_in[4];
  const float* dwq = (const float*)d_in[5];
  const float* dwk = (const float*)d_in[6];
  const float* dwv = (const float*)d_in[7];
  const float* dwo = (const float*)d_in[8];
  float* out = (float*)d_out;

  float* qrope = (float*)d_ws;          // 16*4096 (RoPE'd q, final layout)
  float* krope = qrope + NB * DM;       // 16*4096 (RoPE'd new k)
  float* vraw = krope + NB * DM;        // 16*4096 (new v)
  float* aout = vraw + NB * DM;         // 16*4096 (attention output)
  float* part = aout + NB * DM;         // 16*32*32*132 chunk partials

  qkv_proj_kernel<<<768, 256, 0, stream>>>(x, dwq, dwk, dwv, fr, fi,
                                           qrope, krope, vraw);
  attn_chunk_kernel<<<512, 512, 0, stream>>>(qrope, cache_k, cache_v, part);
  attn_combine_kernel<<<512, 128, 0, stream>>>(qrope, krope, vraw, part, aout);
  oproj_kernel<<<256, 1024, 0, stream>>>(aout, dwo, out);
}